// Round 10
// baseline (141.253 us; speedup 1.0000x reference)
//
#include <hip/hip_runtime.h>

#define NS 16
#define MD 4
#define PD 8
#define BB 256
#define TL 256
#define QV 0.01f
#define RV 0.01f
// covariance filter chunking: 256 chunks x 1 committed step
#define NCHF 256
#define WF   12
// covariance smoother chunking: 256 chunks x 1 committed step
#define NCHS 256
#define WSS  12
// mu chunking (linear error decay)
#define CHM  4
#define NCHM 64
#define WMU  22

// wave-synchronous LDS fence: drain DS queue + pin compiler ordering
#define WSYNC() do { asm volatile("s_waitcnt lgkmcnt(0)" ::: "memory"); \
                     __builtin_amdgcn_sched_barrier(0); } while (0)

#define Z4 make_float4(0.f, 0.f, 0.f, 0.f)

__device__ __forceinline__ float f4c(const float4 v, int i) {
    return i == 0 ? v.x : i == 1 ? v.y : i == 2 ? v.z : v.w;
}

// ---------------------------------------------------------------------------
// kPre: per-t parallel: E[t] = C*A (8x16), SQ[t] = QV*C*C^T + RV*I (8x8)
// ---------------------------------------------------------------------------
__global__ __launch_bounds__(256, 1) void kPre(
    const float* __restrict__ A_seq, const float* __restrict__ C_seq,
    float* __restrict__ E_ws, float* __restrict__ SQ_ws)
{
    const int t = blockIdx.x, tid = threadIdx.x;
    __shared__ float sA[16][17], sC[8][17];
    sA[tid >> 4][tid & 15] = A_seq[t * 256 + tid];
    if (tid < 128) sC[tid >> 4][tid & 15] = C_seq[t * 128 + tid];
    __syncthreads();
    if (tid < 128) {
        const int p = tid >> 4, j = tid & 15;
        float a = 0.f;
        #pragma unroll
        for (int k = 0; k < 16; ++k) a += sC[p][k] * sA[k][j];
        E_ws[t * 128 + tid] = a;
    } else if (tid < 192) {
        const int q2 = tid - 128, p = q2 >> 3, q = q2 & 7;
        float a = 0.f;
        #pragma unroll
        for (int k = 0; k < 16; ++k) a += sC[p][k] * sC[q][k];
        SQ_ws[t * 64 + q2] = QV * a + ((p == q) ? RV : 0.f);
    }
}

// ---------------------------------------------------------------------------
// kF3X: 256 parallel chunks; 3-epoch Riccati warm steps + committed-step
// extension producing G, Bt2 (piggybacked) and J (GJ inverse of the locally
// recomputed Sigp[t+1]).
// ---------------------------------------------------------------------------
__global__ __launch_bounds__(64, 1) void kF3X(
    const float* __restrict__ A_seq, const float* __restrict__ C_seq,
    const float* __restrict__ E_ws, const float* __restrict__ SQ_ws,
    const float* __restrict__ Sig0, const float* __restrict__ B_seq,
    float* __restrict__ K_ws, float* __restrict__ Sigf_ws,
    float* __restrict__ Sigp_ws, float* __restrict__ J_ws,
    float* __restrict__ G_ws, float* __restrict__ Bt2_ws)
{
    const int tlo = blockIdx.x;
    int t0 = tlo - WF; if (t0 < 0) t0 = 0;
    const int nst = tlo + 1 - t0;

    const int l  = threadIdx.x;
    const int r  = l >> 2;
    const int q  = l & 3;
    const int c0 = q * 4;
    const int rc  = l >> 3;
    const int cc0 = (l & 7) * 2;
    const int c8  = l & 7;

    __shared__ float lA[2][16][20];
    __shared__ float lCc[2][8][20];
    __shared__ float lEe[2][8][20];
    __shared__ float lSQs[2][64];
    __shared__ float lSg[2][16][20];
    __shared__ float lT[16][20];
    __shared__ float lW[8][20];
    __shared__ float lCS[8][20];
    __shared__ float lS[64];
    __shared__ float lV[16][20];
    __shared__ float lBs[64];
    __shared__ float lAug[2][16][36];

    float4 sig4;
    if (t0 == 0) {
        sig4 = *(const float4*)(Sig0 + l * 4);
    } else {
        sig4 = make_float4(r == c0 ? 1.f : 0.f, r == c0 + 1 ? 1.f : 0.f,
                           r == c0 + 2 ? 1.f : 0.f, r == c0 + 3 ? 1.f : 0.f);
    }
    float4 a_c  = *(const float4*)(A_seq + t0 * 256 + l * 4);
    float2 cc_c = *(const float2*)(C_seq + t0 * 128 + l * 2);
    float2 e_c  = *(const float2*)(E_ws  + t0 * 128 + l * 2);
    float  sq_c = SQ_ws[t0 * 64 + l];
    float  b_sc = 0.f;
    float4 a1_c = Z4;

    for (int s = 0; s < nst; ++s) {
        const int t = t0 + s;
        const int pb = s & 1;
        const bool commit = (t == tlo);

        *(float4*)&lA[pb][r][c0]    = a_c;
        *(float2*)&lCc[pb][rc][cc0] = cc_c;
        *(float2*)&lEe[pb][rc][cc0] = e_c;
        lSQs[pb][l] = sq_c;
        *(float4*)&lSg[pb][r][c0]   = sig4;
        WSYNC();
        if (s + 1 < nst) {
            a_c  = *(const float4*)(A_seq + (t + 1) * 256 + l * 4);
            cc_c = *(const float2*)(C_seq + (t + 1) * 128 + l * 2);
            e_c  = *(const float2*)(E_ws  + (t + 1) * 128 + l * 2);
            sq_c = SQ_ws[(t + 1) * 64 + l];
        } else {
            b_sc = B_seq[tlo * 64 + l];
            if (tlo < TL - 1)
                a1_c = *(const float4*)(A_seq + (tlo + 1) * 256 + l * 4);
        }

        // --- Epoch 1: T = A*Sig, W = E*Sig ---
        float t4[4] = {0.f, 0.f, 0.f, 0.f};
        #pragma unroll
        for (int kk = 0; kk < 4; ++kk) {
            const float4 a4 = *(const float4*)&lA[pb][r][4 * kk];
            #pragma unroll
            for (int i2 = 0; i2 < 4; ++i2) {
                const float av = f4c(a4, i2);
                const float4 sv = *(const float4*)&lSg[pb][4 * kk + i2][c0];
                t4[0] += av * sv.x; t4[1] += av * sv.y;
                t4[2] += av * sv.z; t4[3] += av * sv.w;
            }
        }
        float w2x = 0.f, w2y = 0.f;
        {
            float4 er[4];
            #pragma unroll
            for (int kk = 0; kk < 4; ++kk) er[kk] = *(const float4*)&lEe[pb][rc][4 * kk];
            #pragma unroll
            for (int kk = 0; kk < 4; ++kk)
                #pragma unroll
                for (int i2 = 0; i2 < 4; ++i2) {
                    const float ev = f4c(er[kk], i2);
                    const float2 s2 = *(const float2*)&lSg[pb][4 * kk + i2][cc0];
                    w2x += ev * s2.x; w2y += ev * s2.y;
                }
        }
        *(float4*)&lT[r][c0]   = make_float4(t4[0], t4[1], t4[2], t4[3]);
        *(float2*)&lW[rc][cc0] = make_float2(w2x, w2y);
        WSYNC();

        // --- Epoch 2: Sigp = T*A^T+Q, CS = W*A^T+QV*C, S = W*E^T+SQ ---
        float4 trr[4], wrow[4];
        #pragma unroll
        for (int kk = 0; kk < 4; ++kk) {
            trr[kk]  = *(const float4*)&lT[r][4 * kk];
            wrow[kk] = *(const float4*)&lW[rc][4 * kk];
        }
        float sp[4];
        #pragma unroll
        for (int i = 0; i < 4; ++i) {
            float a = (r == c0 + i) ? QV : 0.f;
            #pragma unroll
            for (int kk = 0; kk < 4; ++kk) {
                const float4 a4 = *(const float4*)&lA[pb][c0 + i][4 * kk];
                a += trr[kk].x * a4.x + trr[kk].y * a4.y
                   + trr[kk].z * a4.z + trr[kk].w * a4.w;
            }
            sp[i] = a;
        }
        const float2 cpair = *(const float2*)&lCc[pb][rc][cc0];
        float cs2[2];
        #pragma unroll
        for (int cc = 0; cc < 2; ++cc) {
            float a = QV * (cc == 0 ? cpair.x : cpair.y);
            #pragma unroll
            for (int kk = 0; kk < 4; ++kk) {
                const float4 a4 = *(const float4*)&lA[pb][cc0 + cc][4 * kk];
                a += wrow[kk].x * a4.x + wrow[kk].y * a4.y
                   + wrow[kk].z * a4.z + wrow[kk].w * a4.w;
            }
            cs2[cc] = a;
        }
        float sv = lSQs[pb][l];
        #pragma unroll
        for (int kk = 0; kk < 4; ++kk) {
            const float4 e4 = *(const float4*)&lEe[pb][c8][4 * kk];
            sv += wrow[kk].x * e4.x + wrow[kk].y * e4.y
                + wrow[kk].z * e4.z + wrow[kk].w * e4.w;
        }
        *(float2*)&lCS[rc][cc0] = make_float2(cs2[0], cs2[1]);
        lS[l] = sv;
        if (commit) *(float4*)(Sigp_ws + t * 256 + l * 4) =
            make_float4(sp[0], sp[1], sp[2], sp[3]);
        WSYNC();

        // --- Epoch 3: redundant per-lane Cholesky -> K row; U = Sigp - K*CS ---
        float x[8];
        {
            float Lm[8][8]; float Dinv[8];
            #pragma unroll
            for (int r2 = 0; r2 < 8; ++r2)
                #pragma unroll
                for (int c2 = 0; c2 < 8; ++c2)
                    Lm[r2][c2] = (c2 <= r2) ? 0.5f * (lS[r2 * 8 + c2] + lS[c2 * 8 + r2]) : 0.f;
            #pragma unroll
            for (int c2 = 0; c2 < 8; ++c2) {
                float sAcc = Lm[c2][c2];
                #pragma unroll
                for (int k2 = 0; k2 < 8; ++k2) if (k2 < c2) sAcc -= Lm[c2][k2] * Lm[c2][k2];
                const float d = sqrtf(sAcc);
                Dinv[c2] = 1.f / d; Lm[c2][c2] = d;
                #pragma unroll
                for (int r2 = 0; r2 < 8; ++r2) if (r2 > c2) {
                    float s2 = Lm[r2][c2];
                    #pragma unroll
                    for (int k2 = 0; k2 < 8; ++k2) if (k2 < c2) s2 -= Lm[r2][k2] * Lm[c2][k2];
                    Lm[r2][c2] = s2 * Dinv[c2];
                }
            }
            float yv[8];
            #pragma unroll
            for (int c2 = 0; c2 < 8; ++c2) {
                float sAcc = lCS[c2][r];
                #pragma unroll
                for (int k2 = 0; k2 < 8; ++k2) if (k2 < c2) sAcc -= Lm[c2][k2] * yv[k2];
                yv[c2] = sAcc * Dinv[c2];
            }
            #pragma unroll
            for (int c2 = 7; c2 >= 0; --c2) {
                float sAcc = yv[c2];
                #pragma unroll
                for (int k2 = 0; k2 < 8; ++k2) if (k2 > c2) sAcc -= Lm[k2][c2] * x[k2];
                x[c2] = sAcc * Dinv[c2];
            }
        }
        float u[4] = { sp[0], sp[1], sp[2], sp[3] };
        #pragma unroll
        for (int p = 0; p < 8; ++p) {
            const float kv = x[p];
            const float4 cs4 = *(const float4*)&lCS[p][c0];
            u[0] -= kv * cs4.x; u[1] -= kv * cs4.y;
            u[2] -= kv * cs4.z; u[3] -= kv * cs4.w;
        }

        if (!commit) {
            sig4 = make_float4(u[0], u[1], u[2], u[3]);
        } else {
            if (q == 0)      *(float4*)(K_ws + t * 128 + r * 8)     = make_float4(x[0], x[1], x[2], x[3]);
            else if (q == 1) *(float4*)(K_ws + t * 128 + r * 8 + 4) = make_float4(x[4], x[5], x[6], x[7]);

            // G = A - K*E  (piggyback: no new sync)
            const float4 arow = *(const float4*)&lA[pb][r][c0];
            float g4[4] = { arow.x, arow.y, arow.z, arow.w };
            #pragma unroll
            for (int p = 0; p < 8; ++p) {
                const float4 ee = *(const float4*)&lEe[pb][p][c0];
                g4[0] -= x[p] * ee.x; g4[1] -= x[p] * ee.y;
                g4[2] -= x[p] * ee.z; g4[3] -= x[p] * ee.w;
            }
            *(float4*)(G_ws + t * 256 + l * 4) = make_float4(g4[0], g4[1], g4[2], g4[3]);

            *(float4*)&lV[r][c0] = make_float4(u[0], u[1], u[2], u[3]);
            lBs[l] = b_sc;
            WSYNC();
            float o[4];
            #pragma unroll
            for (int i = 0; i < 4; ++i) o[i] = 0.5f * (u[i] + lV[c0 + i][r]);
            sig4 = make_float4(o[0], o[1], o[2], o[3]);
            *(float4*)(Sigf_ws + t * 256 + l * 4) = sig4;

            // Bt2 = B - K*(C*B): per-lane CB column m (redundant, cheap)
            {
                float bt = lBs[l];
                #pragma unroll
                for (int p = 0; p < 8; ++p) {
                    float cb = 0.f;
                    #pragma unroll
                    for (int k = 0; k < 16; ++k) cb += lCc[pb][p][k] * lBs[k * 4 + q];
                    bt -= x[p] * cb;
                }
                Bt2_ws[t * 64 + l] = bt;
            }
        }
    }

    // --- J extension: J = Sigf*A1^T*inv(A1*Sigf*A1^T+Q) ---
    if (tlo < TL - 1) {
        const int pb2 = nst & 1;
        *(float4*)&lSg[pb2][r][c0] = sig4;
        *(float4*)&lA[pb2][r][c0]  = a1_c;
        WSYNC();

        // T2 = A1*Sigf ; FA = Sigf*A1^T
        float t2[4] = {0.f, 0.f, 0.f, 0.f};
        #pragma unroll
        for (int kk = 0; kk < 4; ++kk) {
            const float4 a4 = *(const float4*)&lA[pb2][r][4 * kk];
            #pragma unroll
            for (int i2 = 0; i2 < 4; ++i2) {
                const float av = f4c(a4, i2);
                const float4 sv2 = *(const float4*)&lSg[pb2][4 * kk + i2][c0];
                t2[0] += av * sv2.x; t2[1] += av * sv2.y;
                t2[2] += av * sv2.z; t2[3] += av * sv2.w;
            }
        }
        float fa[4];
        #pragma unroll
        for (int i = 0; i < 4; ++i) {
            float a = 0.f;
            #pragma unroll
            for (int kk = 0; kk < 4; ++kk) {
                const float4 sf4 = *(const float4*)&lSg[pb2][r][4 * kk];
                const float4 a4  = *(const float4*)&lA[pb2][c0 + i][4 * kk];
                a += sf4.x * a4.x + sf4.y * a4.y + sf4.z * a4.z + sf4.w * a4.w;
            }
            fa[i] = a;
        }
        *(float4*)&lT[r][c0] = make_float4(t2[0], t2[1], t2[2], t2[3]);
        *(float4*)&lV[r][c0] = make_float4(fa[0], fa[1], fa[2], fa[3]);
        WSYNC();

        // Sigp2 = T2*A1^T + Q -> augmented [Sigp2 | I]
        float sp2[4];
        #pragma unroll
        for (int i = 0; i < 4; ++i) {
            float a = (r == c0 + i) ? QV : 0.f;
            #pragma unroll
            for (int kk = 0; kk < 4; ++kk) {
                const float4 tt = *(const float4*)&lT[r][4 * kk];
                const float4 a4 = *(const float4*)&lA[pb2][c0 + i][4 * kk];
                a += tt.x * a4.x + tt.y * a4.y + tt.z * a4.z + tt.w * a4.w;
            }
            sp2[i] = a;
        }
        *(float4*)&lAug[0][r][c0] = make_float4(sp2[0], sp2[1], sp2[2], sp2[3]);
        *(float4*)&lAug[0][r][16 + c0] =
            make_float4(r == c0 ? 1.f : 0.f, r == c0 + 1 ? 1.f : 0.f,
                        r == c0 + 2 ? 1.f : 0.f, r == c0 + 3 ? 1.f : 0.f);
        WSYNC();

        #pragma unroll 1
        for (int k = 0; k < 16; ++k) {
            const int cur = k & 1, nxt = cur ^ 1;
            const float piv = 1.f / lAug[cur][k][k];
            const float4 rk  = *(const float4*)&lAug[cur][k][c0];
            const float4 rk2 = *(const float4*)&lAug[cur][k][16 + c0];
            float4 o1, o2;
            if (r == k) {
                o1 = make_float4(rk.x * piv,  rk.y * piv,  rk.z * piv,  rk.w * piv);
                o2 = make_float4(rk2.x * piv, rk2.y * piv, rk2.z * piv, rk2.w * piv);
            } else {
                const float f = lAug[cur][r][k] * piv;
                const float4 w1 = *(const float4*)&lAug[cur][r][c0];
                const float4 w2 = *(const float4*)&lAug[cur][r][16 + c0];
                o1 = make_float4(w1.x - f * rk.x,  w1.y - f * rk.y,
                                 w1.z - f * rk.z,  w1.w - f * rk.w);
                o2 = make_float4(w2.x - f * rk2.x, w2.y - f * rk2.y,
                                 w2.z - f * rk2.z, w2.w - f * rk2.w);
            }
            *(float4*)&lAug[nxt][r][c0]      = o1;
            *(float4*)&lAug[nxt][r][16 + c0] = o2;
            WSYNC();
        }

        float j4[4] = {0.f, 0.f, 0.f, 0.f};
        #pragma unroll
        for (int kk = 0; kk < 4; ++kk) {
            const float4 fv = *(const float4*)&lV[r][4 * kk];
            #pragma unroll
            for (int i2 = 0; i2 < 4; ++i2) {
                const float v = f4c(fv, i2);
                const float4 p4 = *(const float4*)&lAug[0][4 * kk + i2][16 + c0];
                j4[0] += v * p4.x; j4[1] += v * p4.y;
                j4[2] += v * p4.z; j4[3] += v * p4.w;
            }
        }
        *(float4*)(J_ws + tlo * 256 + l * 4) = make_float4(j4[0], j4[1], j4[2], j4[3]);
    }
}

// ---------------------------------------------------------------------------
// kES3: blocks [0,256)      = covariance smoother warm chunks (wave0)
//       blocks [256,1280)   = mu filter warm chunks
//       blocks [1280,2304)  = Sigf broadcast
// ---------------------------------------------------------------------------
__global__ __launch_bounds__(256, 1) void kES3(
    const float* __restrict__ A_seq, const float* __restrict__ B_seq,
    const float* __restrict__ U, const float* __restrict__ Y,
    const float* __restrict__ mu0,
    const float* __restrict__ G_ws, const float* __restrict__ Bt2_ws,
    const float* __restrict__ K_ws, const float* __restrict__ Sigf_ws,
    const float* __restrict__ Sigp_ws, const float* __restrict__ J_ws,
    float* __restrict__ Sigs_ws, float* __restrict__ mus_f_out,
    float* __restrict__ mup_ws, float* __restrict__ Sigs_f_out)
{
    const int bid = blockIdx.x, tid = threadIdx.x;

    if (bid < NCHS) {
        if (tid < 64) {
            const int l   = tid;
            const int r   = l >> 2;
            const int c0  = (l & 3) * 4;
            const int tlo = bid;
            int tstart = tlo + WSS; if (tstart > 254) tstart = 254;

            __shared__ float sJ[2][16][20];
            __shared__ float sD[2][16][20];
            __shared__ float sT1[16][20];
            __shared__ float sV[16][20];

            float4 sS = *(const float4*)(Sigf_ws + (tstart + 1) * 256 + l * 4);
            if (tlo == 255) {
                *(float4*)(Sigs_ws + 255 * 256 + l * 4) = sS;
            }

            float4 j_c  = *(const float4*)(J_ws    + tstart * 256 + l * 4);
            float4 sp_c = *(const float4*)(Sigp_ws + (tstart + 1) * 256 + l * 4);
            float4 sf_c = *(const float4*)(Sigf_ws + tstart * 256 + l * 4);

            for (int t = tstart; t >= tlo; --t) {
                const int pb = t & 1;
                float4 d4 = make_float4(sS.x - sp_c.x, sS.y - sp_c.y,
                                        sS.z - sp_c.z, sS.w - sp_c.w);
                *(float4*)&sJ[pb][r][c0] = j_c;
                *(float4*)&sD[pb][r][c0] = d4;
                WSYNC();
                const float4 sf_use = sf_c;
                if (t > tlo) {
                    j_c  = *(const float4*)(J_ws    + (t - 1) * 256 + l * 4);
                    sp_c = *(const float4*)(Sigp_ws + t * 256 + l * 4);
                    sf_c = *(const float4*)(Sigf_ws + (t - 1) * 256 + l * 4);
                }

                float a4[4] = {0.f, 0.f, 0.f, 0.f};
                #pragma unroll
                for (int kk = 0; kk < 4; ++kk) {
                    const float4 jr = *(const float4*)&sJ[pb][r][4 * kk];
                    #pragma unroll
                    for (int i2 = 0; i2 < 4; ++i2) {
                        const float jv = f4c(jr, i2);
                        const float4 dv = *(const float4*)&sD[pb][4 * kk + i2][c0];
                        a4[0] += jv * dv.x; a4[1] += jv * dv.y;
                        a4[2] += jv * dv.z; a4[3] += jv * dv.w;
                    }
                }
                *(float4*)&sT1[r][c0] = make_float4(a4[0], a4[1], a4[2], a4[3]);
                WSYNC();

                float4 t1r[4];
                #pragma unroll
                for (int kk = 0; kk < 4; ++kk) t1r[kk] = *(const float4*)&sT1[r][4 * kk];
                float v[4];
                #pragma unroll
                for (int i = 0; i < 4; ++i) {
                    float a = f4c(sf_use, i);
                    #pragma unroll
                    for (int kk = 0; kk < 4; ++kk) {
                        const float4 j4 = *(const float4*)&sJ[pb][c0 + i][4 * kk];
                        a += t1r[kk].x * j4.x + t1r[kk].y * j4.y
                           + t1r[kk].z * j4.z + t1r[kk].w * j4.w;
                    }
                    v[i] = a;
                }

                if (t > tlo) {
                    sS = make_float4(v[0], v[1], v[2], v[3]);
                } else {
                    *(float4*)&sV[r][c0] = make_float4(v[0], v[1], v[2], v[3]);
                    WSYNC();
                    float o[4];
                    #pragma unroll
                    for (int i = 0; i < 4; ++i) o[i] = 0.5f * (v[i] + sV[c0 + i][r]);
                    *(float4*)(Sigs_ws + t * 256 + l * 4) =
                        make_float4(o[0], o[1], o[2], o[3]);
                }
            }
        }
    } else if (bid < NCHS + NCHM * 16) {
        // ---- mu filter chunk: mf = G mu + Bt2 u + K y ; mp = A mu + B u ----
        const int eb = bid - NCHS;
        const int ch = eb >> 4;
        const int gq = eb & 15;
        const int w  = tid >> 6;
        const int l  = tid & 63;
        const int g  = l >> 4;
        const int i  = l & 15;
        const int b  = (gq * 4 + w) * 4 + g;
        const int base = l & 48;
        const int tlo  = ch * CHM;
        int t0 = tlo - WMU; if (t0 < 0) t0 = 0;
        const int tend = tlo + CHM;

        float mu = (t0 == 0) ? mu0[i] : 0.f;

        float4 g_c[4], a_c[4] = {Z4, Z4, Z4, Z4}, k_c[2];
        float4 b_c = Z4, bt_c, u_c, y0_c, y1_c;
        {
            const float* Gb = G_ws + t0 * 256 + i * 16;
            #pragma unroll
            for (int kk = 0; kk < 4; ++kk) g_c[kk] = *(const float4*)(Gb + 4 * kk);
            if (t0 >= tlo) {
                const float* Ab = A_seq + t0 * 256 + i * 16;
                #pragma unroll
                for (int kk = 0; kk < 4; ++kk) a_c[kk] = *(const float4*)(Ab + 4 * kk);
                b_c = *(const float4*)(B_seq + t0 * 64 + i * 4);
            }
            k_c[0] = *(const float4*)(K_ws + t0 * 128 + i * 8);
            k_c[1] = *(const float4*)(K_ws + t0 * 128 + i * 8 + 4);
            bt_c = *(const float4*)(Bt2_ws + t0 * 64 + i * 4);
            u_c  = *(const float4*)(U + ((size_t)b * TL + t0) * MD);
            y0_c = *(const float4*)(Y + ((size_t)b * TL + t0) * PD);
            y1_c = *(const float4*)(Y + ((size_t)b * TL + t0) * PD + 4);
        }

        for (int t = t0; t < tend; ++t) {
            float4 g_n[4] = {Z4, Z4, Z4, Z4}, a_n[4] = {Z4, Z4, Z4, Z4};
            float4 k_n[2] = {Z4, Z4};
            float4 b_n = Z4, bt_n = Z4, u_n = Z4, y0_n = Z4, y1_n = Z4;
            if (t + 1 < tend) {
                const float* Gb = G_ws + (t + 1) * 256 + i * 16;
                #pragma unroll
                for (int kk = 0; kk < 4; ++kk) g_n[kk] = *(const float4*)(Gb + 4 * kk);
                if (t + 1 >= tlo) {
                    const float* Ab = A_seq + (t + 1) * 256 + i * 16;
                    #pragma unroll
                    for (int kk = 0; kk < 4; ++kk) a_n[kk] = *(const float4*)(Ab + 4 * kk);
                    b_n = *(const float4*)(B_seq + (t + 1) * 64 + i * 4);
                }
                k_n[0] = *(const float4*)(K_ws + (t + 1) * 128 + i * 8);
                k_n[1] = *(const float4*)(K_ws + (t + 1) * 128 + i * 8 + 4);
                bt_n = *(const float4*)(Bt2_ws + (t + 1) * 64 + i * 4);
                u_n  = *(const float4*)(U + ((size_t)b * TL + t + 1) * MD);
                y0_n = *(const float4*)(Y + ((size_t)b * TL + t + 1) * PD);
                y1_n = *(const float4*)(Y + ((size_t)b * TL + t + 1) * PD + 4);
            }

            const bool com = (t >= tlo);
            float sg0 = 0.f, sg1 = 0.f, sg2 = 0.f, sg3 = 0.f;
            float sa0 = 0.f, sa1 = 0.f, sa2 = 0.f, sa3 = 0.f;
            #pragma unroll
            for (int k4 = 0; k4 < 4; ++k4) {
                const float m0 = __shfl(mu, base + 4 * k4 + 0);
                const float m1 = __shfl(mu, base + 4 * k4 + 1);
                const float m2 = __shfl(mu, base + 4 * k4 + 2);
                const float m3 = __shfl(mu, base + 4 * k4 + 3);
                sg0 += f4c(g_c[k4], 0) * m0;
                sg1 += f4c(g_c[k4], 1) * m1;
                sg2 += f4c(g_c[k4], 2) * m2;
                sg3 += f4c(g_c[k4], 3) * m3;
                if (com) {
                    sa0 += f4c(a_c[k4], 0) * m0;
                    sa1 += f4c(a_c[k4], 1) * m1;
                    sa2 += f4c(a_c[k4], 2) * m2;
                    sa3 += f4c(a_c[k4], 3) * m3;
                }
            }
            float mf = (sg0 + sg1) + (sg2 + sg3);
            #pragma unroll
            for (int m = 0; m < 4; ++m) {
                mf += f4c(bt_c, m) * f4c(u_c, m);
                mf += f4c(k_c[0], m) * f4c(y0_c, m);
                mf += f4c(k_c[1], m) * f4c(y1_c, m);
            }
            if (com) {
                float mp = (sa0 + sa1) + (sa2 + sa3);
                #pragma unroll
                for (int m = 0; m < 4; ++m) mp += f4c(b_c, m) * f4c(u_c, m);
                mup_ws[((size_t)b * TL + t) * NS + i]    = mp;
                mus_f_out[((size_t)b * TL + t) * NS + i] = mf;
            }
            mu = mf;

            #pragma unroll
            for (int kk = 0; kk < 4; ++kk) { g_c[kk] = g_n[kk]; a_c[kk] = a_n[kk]; }
            k_c[0] = k_n[0]; k_c[1] = k_n[1];
            b_c = b_n; bt_c = bt_n; u_c = u_n; y0_c = y0_n; y1_c = y1_n;
        }
    } else {
        // ---- Sigf broadcast ----
        const size_t total = (size_t)BB * TL * 64;
        const int lb = bid - (NCHS + NCHM * 16);
        size_t idx = (size_t)lb * 256 + tid;
        const size_t stride = (size_t)1024 * 256;
        for (size_t x = idx; x < total; x += stride) {
            const size_t e4 = x & 63;
            const size_t t = (x >> 6) & 255;
            ((float4*)Sigs_f_out)[x] = ((const float4*)Sigf_ws)[t * 64 + e4];
        }
    }
}

// ---------------------------------------------------------------------------
// kFD: blocks [0,1024)     = mu smoother warm chunks
//      blocks [1024,2048)  = Sigs broadcast
// ---------------------------------------------------------------------------
__global__ __launch_bounds__(256, 1) void kFD(
    const float* __restrict__ mus_f, const float* __restrict__ mup_ws,
    const float* __restrict__ J_ws, float* __restrict__ mus_s,
    const float* __restrict__ Sigs_ws, float* __restrict__ Sigs_s_out)
{
    const int bid = blockIdx.x, tid = threadIdx.x;

    if (bid < NCHM * 16) {
        const int ch = bid >> 4;
        const int gq = bid & 15;
        const int w  = tid >> 6;
        const int l  = tid & 63;
        const int g  = l >> 4;
        const int i  = l & 15;
        const int b  = (gq * 4 + w) * 4 + g;
        const int base = l & 48;
        const int tlo = ch * CHM;
        const int thi = tlo + CHM - 1;
        int tstart = thi + WMU; if (tstart > 254) tstart = 254;

        float muS = mus_f[((size_t)b * TL + tstart + 1) * NS + i];
        if (thi == 255) mus_s[((size_t)b * TL + 255) * NS + i] = muS;

        float4 j_c[4];
        float f_c, p_c;
        #pragma unroll
        for (int kk = 0; kk < 4; ++kk)
            j_c[kk] = *(const float4*)(J_ws + tstart * 256 + i * 16 + 4 * kk);
        f_c = mus_f[((size_t)b * TL + tstart) * NS + i];
        p_c = mup_ws[((size_t)b * TL + tstart + 1) * NS + i];

        for (int t = tstart; t >= tlo; --t) {
            float4 j_n[4] = {Z4, Z4, Z4, Z4};
            float f_n = 0.f, p_n = 0.f;
            if (t > tlo) {
                #pragma unroll
                for (int kk = 0; kk < 4; ++kk)
                    j_n[kk] = *(const float4*)(J_ws + (t - 1) * 256 + i * 16 + 4 * kk);
                f_n = mus_f[((size_t)b * TL + t - 1) * NS + i];
                p_n = mup_ws[((size_t)b * TL + t) * NS + i];
            }

            const float d = muS - p_c;
            float q0 = 0.f, q1 = 0.f, q2 = 0.f, q3 = 0.f;
            #pragma unroll
            for (int k4 = 0; k4 < 4; ++k4) {
                q0 += f4c(j_c[k4], 0) * __shfl(d, base + 4 * k4 + 0);
                q1 += f4c(j_c[k4], 1) * __shfl(d, base + 4 * k4 + 1);
                q2 += f4c(j_c[k4], 2) * __shfl(d, base + 4 * k4 + 2);
                q3 += f4c(j_c[k4], 3) * __shfl(d, base + 4 * k4 + 3);
            }
            muS = f_c + ((q0 + q1) + (q2 + q3));
            if (t <= thi) mus_s[((size_t)b * TL + t) * NS + i] = muS;

            #pragma unroll
            for (int kk = 0; kk < 4; ++kk) j_c[kk] = j_n[kk];
            f_c = f_n; p_c = p_n;
        }
    } else {
        const size_t total = (size_t)BB * TL * 64;
        const int lb = bid - NCHM * 16;
        size_t idx = (size_t)lb * 256 + tid;
        const size_t stride = (size_t)1024 * 256;
        for (size_t x = idx; x < total; x += stride) {
            const size_t e4 = x & 63;
            const size_t t = (x >> 6) & 255;
            ((float4*)Sigs_s_out)[x] = ((const float4*)Sigs_ws)[t * 64 + e4];
        }
    }
}

// ---------------------------------------------------------------------------
extern "C" void kernel_launch(void* const* d_in, const int* in_sizes, int n_in,
                              void* d_out, int out_size, void* d_ws, size_t ws_size,
                              hipStream_t stream) {
    const float* Y     = (const float*)d_in[0];
    const float* U     = (const float*)d_in[1];
    const float* A_seq = (const float*)d_in[2];
    const float* B_seq = (const float*)d_in[3];
    const float* C_seq = (const float*)d_in[4];
    const float* mu0   = (const float*)d_in[5];
    const float* Sig0  = (const float*)d_in[6];

    float* out = (float*)d_out;
    const size_t nBT = (size_t)BB * TL;
    float* mus_s_out  = out;                         // (B,T,16)
    float* Sigs_s_out = mus_s_out + nBT * NS;        // (B,T,16,16)
    float* mus_f_out  = Sigs_s_out + nBT * NS * NS;  // (B,T,16)
    float* Sigs_f_out = mus_f_out + nBT * NS;        // (B,T,16,16)

    // workspace layout (floats)
    float* w = (float*)d_ws;
    float* K_ws    = w;  w += TL * NS * PD;
    float* Sigf_ws = w;  w += TL * 256;
    float* Sigp_ws = w;  w += TL * 256;
    float* J_ws    = w;  w += TL * 256;
    float* Sigs_ws = w;  w += TL * 256;
    float* G_ws    = w;  w += TL * 256;
    float* Bt2_ws  = w;  w += TL * 64;
    float* E_ws    = w;  w += TL * 128;
    float* SQ_ws   = w;  w += TL * 64;
    float* mup_ws  = w;  w += nBT * NS;

    kPre <<<TL, 256, 0, stream>>>(A_seq, C_seq, E_ws, SQ_ws);
    kF3X <<<NCHF, 64, 0, stream>>>(A_seq, C_seq, E_ws, SQ_ws, Sig0, B_seq,
                                   K_ws, Sigf_ws, Sigp_ws, J_ws, G_ws, Bt2_ws);
    kES3 <<<NCHS + NCHM * 16 + 1024, 256, 0, stream>>>(A_seq, B_seq, U, Y, mu0,
        G_ws, Bt2_ws, K_ws, Sigf_ws, Sigp_ws, J_ws,
        Sigs_ws, mus_f_out, mup_ws, Sigs_f_out);
    kFD  <<<NCHM * 16 + 1024, 256, 0, stream>>>(mus_f_out, mup_ws, J_ws, mus_s_out,
                                                Sigs_ws, Sigs_s_out);
}

// Round 11
// 113.636 us; speedup vs baseline: 1.2430x; 1.2430x over previous
//
#include <hip/hip_runtime.h>

#define NS 16
#define MD 4
#define PD 8
#define BB 256
#define TL 256
#define QV 0.01f
#define RV 0.01f
// covariance filter chunking: 256 chunks x 1 committed step
#define NCHF 256
#define WF   12
// covariance smoother chunking: 256 chunks x 1 committed step
#define NCHS 256
#define WSS  12
// mu chunking (linear error decay) — r9 optimum: fewer, longer chunks
#define CHM  8
#define NCHM 32
#define WMU  26

// wave-synchronous LDS fence: drain DS queue + pin compiler ordering
#define WSYNC() do { asm volatile("s_waitcnt lgkmcnt(0)" ::: "memory"); \
                     __builtin_amdgcn_sched_barrier(0); } while (0)

#define Z4 make_float4(0.f, 0.f, 0.f, 0.f)

__device__ __forceinline__ float f4c(const float4 v, int i) {
    return i == 0 ? v.x : i == 1 ? v.y : i == 2 ? v.z : v.w;
}

// ---------------------------------------------------------------------------
// kPre: per-t parallel: E[t] = C*A (8x16), SQ[t] = QV*C*C^T + RV*I (8x8)
// ---------------------------------------------------------------------------
__global__ __launch_bounds__(256, 1) void kPre(
    const float* __restrict__ A_seq, const float* __restrict__ C_seq,
    float* __restrict__ E_ws, float* __restrict__ SQ_ws)
{
    const int t = blockIdx.x, tid = threadIdx.x;
    __shared__ float sA[16][17], sC[8][17];
    sA[tid >> 4][tid & 15] = A_seq[t * 256 + tid];
    if (tid < 128) sC[tid >> 4][tid & 15] = C_seq[t * 128 + tid];
    __syncthreads();
    if (tid < 128) {
        const int p = tid >> 4, j = tid & 15;
        float a = 0.f;
        #pragma unroll
        for (int k = 0; k < 16; ++k) a += sC[p][k] * sA[k][j];
        E_ws[t * 128 + tid] = a;
    } else if (tid < 192) {
        const int q2 = tid - 128, p = q2 >> 3, q = q2 & 7;
        float a = 0.f;
        #pragma unroll
        for (int k = 0; k < 16; ++k) a += sC[p][k] * sC[q][k];
        SQ_ws[t * 64 + q2] = QV * a + ((p == q) ? RV : 0.f);
    }
}

// ---------------------------------------------------------------------------
// kF3X: 256 parallel chunks; 3-epoch Riccati warm steps + committed-step
// extension producing G, Bt2 (piggybacked) and J (GJ inverse of the locally
// recomputed Sigp[t+1]).
// ---------------------------------------------------------------------------
__global__ __launch_bounds__(64, 1) void kF3X(
    const float* __restrict__ A_seq, const float* __restrict__ C_seq,
    const float* __restrict__ E_ws, const float* __restrict__ SQ_ws,
    const float* __restrict__ Sig0, const float* __restrict__ B_seq,
    float* __restrict__ K_ws, float* __restrict__ Sigf_ws,
    float* __restrict__ Sigp_ws, float* __restrict__ J_ws,
    float* __restrict__ G_ws, float* __restrict__ Bt2_ws)
{
    const int tlo = blockIdx.x;
    int t0 = tlo - WF; if (t0 < 0) t0 = 0;
    const int nst = tlo + 1 - t0;

    const int l  = threadIdx.x;
    const int r  = l >> 2;
    const int q  = l & 3;
    const int c0 = q * 4;
    const int rc  = l >> 3;
    const int cc0 = (l & 7) * 2;
    const int c8  = l & 7;

    __shared__ float lA[2][16][20];
    __shared__ float lCc[2][8][20];
    __shared__ float lEe[2][8][20];
    __shared__ float lSQs[2][64];
    __shared__ float lSg[2][16][20];
    __shared__ float lT[16][20];
    __shared__ float lW[8][20];
    __shared__ float lCS[8][20];
    __shared__ float lS[64];
    __shared__ float lV[16][20];
    __shared__ float lBs[64];
    __shared__ float lAug[2][16][36];

    float4 sig4;
    if (t0 == 0) {
        sig4 = *(const float4*)(Sig0 + l * 4);
    } else {
        sig4 = make_float4(r == c0 ? 1.f : 0.f, r == c0 + 1 ? 1.f : 0.f,
                           r == c0 + 2 ? 1.f : 0.f, r == c0 + 3 ? 1.f : 0.f);
    }
    float4 a_c  = *(const float4*)(A_seq + t0 * 256 + l * 4);
    float2 cc_c = *(const float2*)(C_seq + t0 * 128 + l * 2);
    float2 e_c  = *(const float2*)(E_ws  + t0 * 128 + l * 2);
    float  sq_c = SQ_ws[t0 * 64 + l];
    float  b_sc = 0.f;
    float4 a1_c = Z4;

    for (int s = 0; s < nst; ++s) {
        const int t = t0 + s;
        const int pb = s & 1;
        const bool commit = (t == tlo);

        *(float4*)&lA[pb][r][c0]    = a_c;
        *(float2*)&lCc[pb][rc][cc0] = cc_c;
        *(float2*)&lEe[pb][rc][cc0] = e_c;
        lSQs[pb][l] = sq_c;
        *(float4*)&lSg[pb][r][c0]   = sig4;
        WSYNC();
        if (s + 1 < nst) {
            a_c  = *(const float4*)(A_seq + (t + 1) * 256 + l * 4);
            cc_c = *(const float2*)(C_seq + (t + 1) * 128 + l * 2);
            e_c  = *(const float2*)(E_ws  + (t + 1) * 128 + l * 2);
            sq_c = SQ_ws[(t + 1) * 64 + l];
        } else {
            b_sc = B_seq[tlo * 64 + l];
            if (tlo < TL - 1)
                a1_c = *(const float4*)(A_seq + (tlo + 1) * 256 + l * 4);
        }

        // --- Epoch 1: T = A*Sig, W = E*Sig ---
        float t4[4] = {0.f, 0.f, 0.f, 0.f};
        #pragma unroll
        for (int kk = 0; kk < 4; ++kk) {
            const float4 a4 = *(const float4*)&lA[pb][r][4 * kk];
            #pragma unroll
            for (int i2 = 0; i2 < 4; ++i2) {
                const float av = f4c(a4, i2);
                const float4 sv = *(const float4*)&lSg[pb][4 * kk + i2][c0];
                t4[0] += av * sv.x; t4[1] += av * sv.y;
                t4[2] += av * sv.z; t4[3] += av * sv.w;
            }
        }
        float w2x = 0.f, w2y = 0.f;
        {
            float4 er[4];
            #pragma unroll
            for (int kk = 0; kk < 4; ++kk) er[kk] = *(const float4*)&lEe[pb][rc][4 * kk];
            #pragma unroll
            for (int kk = 0; kk < 4; ++kk)
                #pragma unroll
                for (int i2 = 0; i2 < 4; ++i2) {
                    const float ev = f4c(er[kk], i2);
                    const float2 s2 = *(const float2*)&lSg[pb][4 * kk + i2][cc0];
                    w2x += ev * s2.x; w2y += ev * s2.y;
                }
        }
        *(float4*)&lT[r][c0]   = make_float4(t4[0], t4[1], t4[2], t4[3]);
        *(float2*)&lW[rc][cc0] = make_float2(w2x, w2y);
        WSYNC();

        // --- Epoch 2: Sigp = T*A^T+Q, CS = W*A^T+QV*C, S = W*E^T+SQ ---
        float4 trr[4], wrow[4];
        #pragma unroll
        for (int kk = 0; kk < 4; ++kk) {
            trr[kk]  = *(const float4*)&lT[r][4 * kk];
            wrow[kk] = *(const float4*)&lW[rc][4 * kk];
        }
        float sp[4];
        #pragma unroll
        for (int i = 0; i < 4; ++i) {
            float a = (r == c0 + i) ? QV : 0.f;
            #pragma unroll
            for (int kk = 0; kk < 4; ++kk) {
                const float4 a4 = *(const float4*)&lA[pb][c0 + i][4 * kk];
                a += trr[kk].x * a4.x + trr[kk].y * a4.y
                   + trr[kk].z * a4.z + trr[kk].w * a4.w;
            }
            sp[i] = a;
        }
        const float2 cpair = *(const float2*)&lCc[pb][rc][cc0];
        float cs2[2];
        #pragma unroll
        for (int cc = 0; cc < 2; ++cc) {
            float a = QV * (cc == 0 ? cpair.x : cpair.y);
            #pragma unroll
            for (int kk = 0; kk < 4; ++kk) {
                const float4 a4 = *(const float4*)&lA[pb][cc0 + cc][4 * kk];
                a += wrow[kk].x * a4.x + wrow[kk].y * a4.y
                   + wrow[kk].z * a4.z + wrow[kk].w * a4.w;
            }
            cs2[cc] = a;
        }
        float sv = lSQs[pb][l];
        #pragma unroll
        for (int kk = 0; kk < 4; ++kk) {
            const float4 e4 = *(const float4*)&lEe[pb][c8][4 * kk];
            sv += wrow[kk].x * e4.x + wrow[kk].y * e4.y
                + wrow[kk].z * e4.z + wrow[kk].w * e4.w;
        }
        *(float2*)&lCS[rc][cc0] = make_float2(cs2[0], cs2[1]);
        lS[l] = sv;
        if (commit) *(float4*)(Sigp_ws + t * 256 + l * 4) =
            make_float4(sp[0], sp[1], sp[2], sp[3]);
        WSYNC();

        // --- Epoch 3: redundant per-lane Cholesky -> K row; U = Sigp - K*CS ---
        float x[8];
        {
            float Lm[8][8]; float Dinv[8];
            #pragma unroll
            for (int r2 = 0; r2 < 8; ++r2)
                #pragma unroll
                for (int c2 = 0; c2 < 8; ++c2)
                    Lm[r2][c2] = (c2 <= r2) ? 0.5f * (lS[r2 * 8 + c2] + lS[c2 * 8 + r2]) : 0.f;
            #pragma unroll
            for (int c2 = 0; c2 < 8; ++c2) {
                float sAcc = Lm[c2][c2];
                #pragma unroll
                for (int k2 = 0; k2 < 8; ++k2) if (k2 < c2) sAcc -= Lm[c2][k2] * Lm[c2][k2];
                const float d = sqrtf(sAcc);
                Dinv[c2] = 1.f / d; Lm[c2][c2] = d;
                #pragma unroll
                for (int r2 = 0; r2 < 8; ++r2) if (r2 > c2) {
                    float s2 = Lm[r2][c2];
                    #pragma unroll
                    for (int k2 = 0; k2 < 8; ++k2) if (k2 < c2) s2 -= Lm[r2][k2] * Lm[c2][k2];
                    Lm[r2][c2] = s2 * Dinv[c2];
                }
            }
            float yv[8];
            #pragma unroll
            for (int c2 = 0; c2 < 8; ++c2) {
                float sAcc = lCS[c2][r];
                #pragma unroll
                for (int k2 = 0; k2 < 8; ++k2) if (k2 < c2) sAcc -= Lm[c2][k2] * yv[k2];
                yv[c2] = sAcc * Dinv[c2];
            }
            #pragma unroll
            for (int c2 = 7; c2 >= 0; --c2) {
                float sAcc = yv[c2];
                #pragma unroll
                for (int k2 = 0; k2 < 8; ++k2) if (k2 > c2) sAcc -= Lm[k2][c2] * x[k2];
                x[c2] = sAcc * Dinv[c2];
            }
        }
        float u[4] = { sp[0], sp[1], sp[2], sp[3] };
        #pragma unroll
        for (int p = 0; p < 8; ++p) {
            const float kv = x[p];
            const float4 cs4 = *(const float4*)&lCS[p][c0];
            u[0] -= kv * cs4.x; u[1] -= kv * cs4.y;
            u[2] -= kv * cs4.z; u[3] -= kv * cs4.w;
        }

        if (!commit) {
            sig4 = make_float4(u[0], u[1], u[2], u[3]);
        } else {
            if (q == 0)      *(float4*)(K_ws + t * 128 + r * 8)     = make_float4(x[0], x[1], x[2], x[3]);
            else if (q == 1) *(float4*)(K_ws + t * 128 + r * 8 + 4) = make_float4(x[4], x[5], x[6], x[7]);

            // G = A - K*E  (piggyback: no new sync)
            const float4 arow = *(const float4*)&lA[pb][r][c0];
            float g4[4] = { arow.x, arow.y, arow.z, arow.w };
            #pragma unroll
            for (int p = 0; p < 8; ++p) {
                const float4 ee = *(const float4*)&lEe[pb][p][c0];
                g4[0] -= x[p] * ee.x; g4[1] -= x[p] * ee.y;
                g4[2] -= x[p] * ee.z; g4[3] -= x[p] * ee.w;
            }
            *(float4*)(G_ws + t * 256 + l * 4) = make_float4(g4[0], g4[1], g4[2], g4[3]);

            *(float4*)&lV[r][c0] = make_float4(u[0], u[1], u[2], u[3]);
            lBs[l] = b_sc;
            WSYNC();
            float o[4];
            #pragma unroll
            for (int i = 0; i < 4; ++i) o[i] = 0.5f * (u[i] + lV[c0 + i][r]);
            sig4 = make_float4(o[0], o[1], o[2], o[3]);
            *(float4*)(Sigf_ws + t * 256 + l * 4) = sig4;

            // Bt2 = B - K*(C*B): per-lane CB column m (redundant, cheap)
            {
                float bt = lBs[l];
                #pragma unroll
                for (int p = 0; p < 8; ++p) {
                    float cb = 0.f;
                    #pragma unroll
                    for (int k = 0; k < 16; ++k) cb += lCc[pb][p][k] * lBs[k * 4 + q];
                    bt -= x[p] * cb;
                }
                Bt2_ws[t * 64 + l] = bt;
            }
        }
    }

    // --- J extension: J = Sigf*A1^T*inv(A1*Sigf*A1^T+Q) ---
    if (tlo < TL - 1) {
        const int pb2 = nst & 1;
        *(float4*)&lSg[pb2][r][c0] = sig4;
        *(float4*)&lA[pb2][r][c0]  = a1_c;
        WSYNC();

        // T2 = A1*Sigf ; FA = Sigf*A1^T
        float t2[4] = {0.f, 0.f, 0.f, 0.f};
        #pragma unroll
        for (int kk = 0; kk < 4; ++kk) {
            const float4 a4 = *(const float4*)&lA[pb2][r][4 * kk];
            #pragma unroll
            for (int i2 = 0; i2 < 4; ++i2) {
                const float av = f4c(a4, i2);
                const float4 sv2 = *(const float4*)&lSg[pb2][4 * kk + i2][c0];
                t2[0] += av * sv2.x; t2[1] += av * sv2.y;
                t2[2] += av * sv2.z; t2[3] += av * sv2.w;
            }
        }
        float fa[4];
        #pragma unroll
        for (int i = 0; i < 4; ++i) {
            float a = 0.f;
            #pragma unroll
            for (int kk = 0; kk < 4; ++kk) {
                const float4 sf4 = *(const float4*)&lSg[pb2][r][4 * kk];
                const float4 a4  = *(const float4*)&lA[pb2][c0 + i][4 * kk];
                a += sf4.x * a4.x + sf4.y * a4.y + sf4.z * a4.z + sf4.w * a4.w;
            }
            fa[i] = a;
        }
        *(float4*)&lT[r][c0] = make_float4(t2[0], t2[1], t2[2], t2[3]);
        *(float4*)&lV[r][c0] = make_float4(fa[0], fa[1], fa[2], fa[3]);
        WSYNC();

        // Sigp2 = T2*A1^T + Q -> augmented [Sigp2 | I]
        float sp2[4];
        #pragma unroll
        for (int i = 0; i < 4; ++i) {
            float a = (r == c0 + i) ? QV : 0.f;
            #pragma unroll
            for (int kk = 0; kk < 4; ++kk) {
                const float4 tt = *(const float4*)&lT[r][4 * kk];
                const float4 a4 = *(const float4*)&lA[pb2][c0 + i][4 * kk];
                a += tt.x * a4.x + tt.y * a4.y + tt.z * a4.z + tt.w * a4.w;
            }
            sp2[i] = a;
        }
        *(float4*)&lAug[0][r][c0] = make_float4(sp2[0], sp2[1], sp2[2], sp2[3]);
        *(float4*)&lAug[0][r][16 + c0] =
            make_float4(r == c0 ? 1.f : 0.f, r == c0 + 1 ? 1.f : 0.f,
                        r == c0 + 2 ? 1.f : 0.f, r == c0 + 3 ? 1.f : 0.f);
        WSYNC();

        #pragma unroll 1
        for (int k = 0; k < 16; ++k) {
            const int cur = k & 1, nxt = cur ^ 1;
            const float piv = 1.f / lAug[cur][k][k];
            const float4 rk  = *(const float4*)&lAug[cur][k][c0];
            const float4 rk2 = *(const float4*)&lAug[cur][k][16 + c0];
            float4 o1, o2;
            if (r == k) {
                o1 = make_float4(rk.x * piv,  rk.y * piv,  rk.z * piv,  rk.w * piv);
                o2 = make_float4(rk2.x * piv, rk2.y * piv, rk2.z * piv, rk2.w * piv);
            } else {
                const float f = lAug[cur][r][k] * piv;
                const float4 w1 = *(const float4*)&lAug[cur][r][c0];
                const float4 w2 = *(const float4*)&lAug[cur][r][16 + c0];
                o1 = make_float4(w1.x - f * rk.x,  w1.y - f * rk.y,
                                 w1.z - f * rk.z,  w1.w - f * rk.w);
                o2 = make_float4(w2.x - f * rk2.x, w2.y - f * rk2.y,
                                 w2.z - f * rk2.z, w2.w - f * rk2.w);
            }
            *(float4*)&lAug[nxt][r][c0]      = o1;
            *(float4*)&lAug[nxt][r][16 + c0] = o2;
            WSYNC();
        }

        float j4[4] = {0.f, 0.f, 0.f, 0.f};
        #pragma unroll
        for (int kk = 0; kk < 4; ++kk) {
            const float4 fv = *(const float4*)&lV[r][4 * kk];
            #pragma unroll
            for (int i2 = 0; i2 < 4; ++i2) {
                const float v = f4c(fv, i2);
                const float4 p4 = *(const float4*)&lAug[0][4 * kk + i2][16 + c0];
                j4[0] += v * p4.x; j4[1] += v * p4.y;
                j4[2] += v * p4.z; j4[3] += v * p4.w;
            }
        }
        *(float4*)(J_ws + tlo * 256 + l * 4) = make_float4(j4[0], j4[1], j4[2], j4[3]);
    }
}

// ---------------------------------------------------------------------------
// kES3: blocks [0,256)     = covariance smoother warm chunks (wave0)
//       blocks [256,768)   = mu filter warm chunks
//       blocks [768,1792)  = Sigf broadcast
// ---------------------------------------------------------------------------
__global__ __launch_bounds__(256, 1) void kES3(
    const float* __restrict__ A_seq, const float* __restrict__ B_seq,
    const float* __restrict__ U, const float* __restrict__ Y,
    const float* __restrict__ mu0,
    const float* __restrict__ G_ws, const float* __restrict__ Bt2_ws,
    const float* __restrict__ K_ws, const float* __restrict__ Sigf_ws,
    const float* __restrict__ Sigp_ws, const float* __restrict__ J_ws,
    float* __restrict__ Sigs_ws, float* __restrict__ mus_f_out,
    float* __restrict__ mup_ws, float* __restrict__ Sigs_f_out)
{
    const int bid = blockIdx.x, tid = threadIdx.x;

    if (bid < NCHS) {
        if (tid < 64) {
            const int l   = tid;
            const int r   = l >> 2;
            const int c0  = (l & 3) * 4;
            const int tlo = bid;
            int tstart = tlo + WSS; if (tstart > 254) tstart = 254;

            __shared__ float sJ[2][16][20];
            __shared__ float sD[2][16][20];
            __shared__ float sT1[16][20];
            __shared__ float sV[16][20];

            float4 sS = *(const float4*)(Sigf_ws + (tstart + 1) * 256 + l * 4);
            if (tlo == 255) {
                *(float4*)(Sigs_ws + 255 * 256 + l * 4) = sS;
            }

            float4 j_c  = *(const float4*)(J_ws    + tstart * 256 + l * 4);
            float4 sp_c = *(const float4*)(Sigp_ws + (tstart + 1) * 256 + l * 4);
            float4 sf_c = *(const float4*)(Sigf_ws + tstart * 256 + l * 4);

            for (int t = tstart; t >= tlo; --t) {
                const int pb = t & 1;
                float4 d4 = make_float4(sS.x - sp_c.x, sS.y - sp_c.y,
                                        sS.z - sp_c.z, sS.w - sp_c.w);
                *(float4*)&sJ[pb][r][c0] = j_c;
                *(float4*)&sD[pb][r][c0] = d4;
                WSYNC();
                const float4 sf_use = sf_c;
                if (t > tlo) {
                    j_c  = *(const float4*)(J_ws    + (t - 1) * 256 + l * 4);
                    sp_c = *(const float4*)(Sigp_ws + t * 256 + l * 4);
                    sf_c = *(const float4*)(Sigf_ws + (t - 1) * 256 + l * 4);
                }

                float a4[4] = {0.f, 0.f, 0.f, 0.f};
                #pragma unroll
                for (int kk = 0; kk < 4; ++kk) {
                    const float4 jr = *(const float4*)&sJ[pb][r][4 * kk];
                    #pragma unroll
                    for (int i2 = 0; i2 < 4; ++i2) {
                        const float jv = f4c(jr, i2);
                        const float4 dv = *(const float4*)&sD[pb][4 * kk + i2][c0];
                        a4[0] += jv * dv.x; a4[1] += jv * dv.y;
                        a4[2] += jv * dv.z; a4[3] += jv * dv.w;
                    }
                }
                *(float4*)&sT1[r][c0] = make_float4(a4[0], a4[1], a4[2], a4[3]);
                WSYNC();

                float4 t1r[4];
                #pragma unroll
                for (int kk = 0; kk < 4; ++kk) t1r[kk] = *(const float4*)&sT1[r][4 * kk];
                float v[4];
                #pragma unroll
                for (int i = 0; i < 4; ++i) {
                    float a = f4c(sf_use, i);
                    #pragma unroll
                    for (int kk = 0; kk < 4; ++kk) {
                        const float4 j4 = *(const float4*)&sJ[pb][c0 + i][4 * kk];
                        a += t1r[kk].x * j4.x + t1r[kk].y * j4.y
                           + t1r[kk].z * j4.z + t1r[kk].w * j4.w;
                    }
                    v[i] = a;
                }

                if (t > tlo) {
                    sS = make_float4(v[0], v[1], v[2], v[3]);
                } else {
                    *(float4*)&sV[r][c0] = make_float4(v[0], v[1], v[2], v[3]);
                    WSYNC();
                    float o[4];
                    #pragma unroll
                    for (int i = 0; i < 4; ++i) o[i] = 0.5f * (v[i] + sV[c0 + i][r]);
                    *(float4*)(Sigs_ws + t * 256 + l * 4) =
                        make_float4(o[0], o[1], o[2], o[3]);
                }
            }
        }
    } else if (bid < NCHS + NCHM * 16) {
        // ---- mu filter chunk: mf = G mu + Bt2 u + K y ; mp = A mu + B u ----
        const int eb = bid - NCHS;
        const int ch = eb >> 4;
        const int gq = eb & 15;
        const int w  = tid >> 6;
        const int l  = tid & 63;
        const int g  = l >> 4;
        const int i  = l & 15;
        const int b  = (gq * 4 + w) * 4 + g;
        const int base = l & 48;
        const int tlo  = ch * CHM;
        int t0 = tlo - WMU; if (t0 < 0) t0 = 0;
        const int tend = tlo + CHM;

        float mu = (t0 == 0) ? mu0[i] : 0.f;

        float4 g_c[4], a_c[4] = {Z4, Z4, Z4, Z4}, k_c[2];
        float4 b_c = Z4, bt_c, u_c, y0_c, y1_c;
        {
            const float* Gb = G_ws + t0 * 256 + i * 16;
            #pragma unroll
            for (int kk = 0; kk < 4; ++kk) g_c[kk] = *(const float4*)(Gb + 4 * kk);
            if (t0 >= tlo) {
                const float* Ab = A_seq + t0 * 256 + i * 16;
                #pragma unroll
                for (int kk = 0; kk < 4; ++kk) a_c[kk] = *(const float4*)(Ab + 4 * kk);
                b_c = *(const float4*)(B_seq + t0 * 64 + i * 4);
            }
            k_c[0] = *(const float4*)(K_ws + t0 * 128 + i * 8);
            k_c[1] = *(const float4*)(K_ws + t0 * 128 + i * 8 + 4);
            bt_c = *(const float4*)(Bt2_ws + t0 * 64 + i * 4);
            u_c  = *(const float4*)(U + ((size_t)b * TL + t0) * MD);
            y0_c = *(const float4*)(Y + ((size_t)b * TL + t0) * PD);
            y1_c = *(const float4*)(Y + ((size_t)b * TL + t0) * PD + 4);
        }

        for (int t = t0; t < tend; ++t) {
            float4 g_n[4] = {Z4, Z4, Z4, Z4}, a_n[4] = {Z4, Z4, Z4, Z4};
            float4 k_n[2] = {Z4, Z4};
            float4 b_n = Z4, bt_n = Z4, u_n = Z4, y0_n = Z4, y1_n = Z4;
            if (t + 1 < tend) {
                const float* Gb = G_ws + (t + 1) * 256 + i * 16;
                #pragma unroll
                for (int kk = 0; kk < 4; ++kk) g_n[kk] = *(const float4*)(Gb + 4 * kk);
                if (t + 1 >= tlo) {
                    const float* Ab = A_seq + (t + 1) * 256 + i * 16;
                    #pragma unroll
                    for (int kk = 0; kk < 4; ++kk) a_n[kk] = *(const float4*)(Ab + 4 * kk);
                    b_n = *(const float4*)(B_seq + (t + 1) * 64 + i * 4);
                }
                k_n[0] = *(const float4*)(K_ws + (t + 1) * 128 + i * 8);
                k_n[1] = *(const float4*)(K_ws + (t + 1) * 128 + i * 8 + 4);
                bt_n = *(const float4*)(Bt2_ws + (t + 1) * 64 + i * 4);
                u_n  = *(const float4*)(U + ((size_t)b * TL + t + 1) * MD);
                y0_n = *(const float4*)(Y + ((size_t)b * TL + t + 1) * PD);
                y1_n = *(const float4*)(Y + ((size_t)b * TL + t + 1) * PD + 4);
            }

            const bool com = (t >= tlo);
            float sg0 = 0.f, sg1 = 0.f, sg2 = 0.f, sg3 = 0.f;
            float sa0 = 0.f, sa1 = 0.f, sa2 = 0.f, sa3 = 0.f;
            #pragma unroll
            for (int k4 = 0; k4 < 4; ++k4) {
                const float m0 = __shfl(mu, base + 4 * k4 + 0);
                const float m1 = __shfl(mu, base + 4 * k4 + 1);
                const float m2 = __shfl(mu, base + 4 * k4 + 2);
                const float m3 = __shfl(mu, base + 4 * k4 + 3);
                sg0 += f4c(g_c[k4], 0) * m0;
                sg1 += f4c(g_c[k4], 1) * m1;
                sg2 += f4c(g_c[k4], 2) * m2;
                sg3 += f4c(g_c[k4], 3) * m3;
                if (com) {
                    sa0 += f4c(a_c[k4], 0) * m0;
                    sa1 += f4c(a_c[k4], 1) * m1;
                    sa2 += f4c(a_c[k4], 2) * m2;
                    sa3 += f4c(a_c[k4], 3) * m3;
                }
            }
            float mf = (sg0 + sg1) + (sg2 + sg3);
            #pragma unroll
            for (int m = 0; m < 4; ++m) {
                mf += f4c(bt_c, m) * f4c(u_c, m);
                mf += f4c(k_c[0], m) * f4c(y0_c, m);
                mf += f4c(k_c[1], m) * f4c(y1_c, m);
            }
            if (com) {
                float mp = (sa0 + sa1) + (sa2 + sa3);
                #pragma unroll
                for (int m = 0; m < 4; ++m) mp += f4c(b_c, m) * f4c(u_c, m);
                mup_ws[((size_t)b * TL + t) * NS + i]    = mp;
                mus_f_out[((size_t)b * TL + t) * NS + i] = mf;
            }
            mu = mf;

            #pragma unroll
            for (int kk = 0; kk < 4; ++kk) { g_c[kk] = g_n[kk]; a_c[kk] = a_n[kk]; }
            k_c[0] = k_n[0]; k_c[1] = k_n[1];
            b_c = b_n; bt_c = bt_n; u_c = u_n; y0_c = y0_n; y1_c = y1_n;
        }
    } else {
        // ---- Sigf broadcast ----
        const size_t total = (size_t)BB * TL * 64;
        const int lb = bid - (NCHS + NCHM * 16);
        size_t idx = (size_t)lb * 256 + tid;
        const size_t stride = (size_t)1024 * 256;
        for (size_t x = idx; x < total; x += stride) {
            const size_t e4 = x & 63;
            const size_t t = (x >> 6) & 255;
            ((float4*)Sigs_f_out)[x] = ((const float4*)Sigf_ws)[t * 64 + e4];
        }
    }
}

// ---------------------------------------------------------------------------
// kFD: blocks [0,512)     = mu smoother warm chunks
//      blocks [512,1536)  = Sigs broadcast
// ---------------------------------------------------------------------------
__global__ __launch_bounds__(256, 1) void kFD(
    const float* __restrict__ mus_f, const float* __restrict__ mup_ws,
    const float* __restrict__ J_ws, float* __restrict__ mus_s,
    const float* __restrict__ Sigs_ws, float* __restrict__ Sigs_s_out)
{
    const int bid = blockIdx.x, tid = threadIdx.x;

    if (bid < NCHM * 16) {
        const int ch = bid >> 4;
        const int gq = bid & 15;
        const int w  = tid >> 6;
        const int l  = tid & 63;
        const int g  = l >> 4;
        const int i  = l & 15;
        const int b  = (gq * 4 + w) * 4 + g;
        const int base = l & 48;
        const int tlo = ch * CHM;
        const int thi = tlo + CHM - 1;
        int tstart = thi + WMU; if (tstart > 254) tstart = 254;

        float muS = mus_f[((size_t)b * TL + tstart + 1) * NS + i];
        if (thi == 255) mus_s[((size_t)b * TL + 255) * NS + i] = muS;

        float4 j_c[4];
        float f_c, p_c;
        #pragma unroll
        for (int kk = 0; kk < 4; ++kk)
            j_c[kk] = *(const float4*)(J_ws + tstart * 256 + i * 16 + 4 * kk);
        f_c = mus_f[((size_t)b * TL + tstart) * NS + i];
        p_c = mup_ws[((size_t)b * TL + tstart + 1) * NS + i];

        for (int t = tstart; t >= tlo; --t) {
            float4 j_n[4] = {Z4, Z4, Z4, Z4};
            float f_n = 0.f, p_n = 0.f;
            if (t > tlo) {
                #pragma unroll
                for (int kk = 0; kk < 4; ++kk)
                    j_n[kk] = *(const float4*)(J_ws + (t - 1) * 256 + i * 16 + 4 * kk);
                f_n = mus_f[((size_t)b * TL + t - 1) * NS + i];
                p_n = mup_ws[((size_t)b * TL + t) * NS + i];
            }

            const float d = muS - p_c;
            float q0 = 0.f, q1 = 0.f, q2 = 0.f, q3 = 0.f;
            #pragma unroll
            for (int k4 = 0; k4 < 4; ++k4) {
                q0 += f4c(j_c[k4], 0) * __shfl(d, base + 4 * k4 + 0);
                q1 += f4c(j_c[k4], 1) * __shfl(d, base + 4 * k4 + 1);
                q2 += f4c(j_c[k4], 2) * __shfl(d, base + 4 * k4 + 2);
                q3 += f4c(j_c[k4], 3) * __shfl(d, base + 4 * k4 + 3);
            }
            muS = f_c + ((q0 + q1) + (q2 + q3));
            if (t <= thi) mus_s[((size_t)b * TL + t) * NS + i] = muS;

            #pragma unroll
            for (int kk = 0; kk < 4; ++kk) j_c[kk] = j_n[kk];
            f_c = f_n; p_c = p_n;
        }
    } else {
        const size_t total = (size_t)BB * TL * 64;
        const int lb = bid - NCHM * 16;
        size_t idx = (size_t)lb * 256 + tid;
        const size_t stride = (size_t)1024 * 256;
        for (size_t x = idx; x < total; x += stride) {
            const size_t e4 = x & 63;
            const size_t t = (x >> 6) & 255;
            ((float4*)Sigs_s_out)[x] = ((const float4*)Sigs_ws)[t * 64 + e4];
        }
    }
}

// ---------------------------------------------------------------------------
extern "C" void kernel_launch(void* const* d_in, const int* in_sizes, int n_in,
                              void* d_out, int out_size, void* d_ws, size_t ws_size,
                              hipStream_t stream) {
    const float* Y     = (const float*)d_in[0];
    const float* U     = (const float*)d_in[1];
    const float* A_seq = (const float*)d_in[2];
    const float* B_seq = (const float*)d_in[3];
    const float* C_seq = (const float*)d_in[4];
    const float* mu0   = (const float*)d_in[5];
    const float* Sig0  = (const float*)d_in[6];

    float* out = (float*)d_out;
    const size_t nBT = (size_t)BB * TL;
    float* mus_s_out  = out;                         // (B,T,16)
    float* Sigs_s_out = mus_s_out + nBT * NS;        // (B,T,16,16)
    float* mus_f_out  = Sigs_s_out + nBT * NS * NS;  // (B,T,16)
    float* Sigs_f_out = mus_f_out + nBT * NS;        // (B,T,16,16)

    // workspace layout (floats)
    float* w = (float*)d_ws;
    float* K_ws    = w;  w += TL * NS * PD;
    float* Sigf_ws = w;  w += TL * 256;
    float* Sigp_ws = w;  w += TL * 256;
    float* J_ws    = w;  w += TL * 256;
    float* Sigs_ws = w;  w += TL * 256;
    float* G_ws    = w;  w += TL * 256;
    float* Bt2_ws  = w;  w += TL * 64;
    float* E_ws    = w;  w += TL * 128;
    float* SQ_ws   = w;  w += TL * 64;
    float* mup_ws  = w;  w += nBT * NS;

    kPre <<<TL, 256, 0, stream>>>(A_seq, C_seq, E_ws, SQ_ws);
    kF3X <<<NCHF, 64, 0, stream>>>(A_seq, C_seq, E_ws, SQ_ws, Sig0, B_seq,
                                   K_ws, Sigf_ws, Sigp_ws, J_ws, G_ws, Bt2_ws);
    kES3 <<<NCHS + NCHM * 16 + 1024, 256, 0, stream>>>(A_seq, B_seq, U, Y, mu0,
        G_ws, Bt2_ws, K_ws, Sigf_ws, Sigp_ws, J_ws,
        Sigs_ws, mus_f_out, mup_ws, Sigs_f_out);
    kFD  <<<NCHM * 16 + 1024, 256, 0, stream>>>(mus_f_out, mup_ws, J_ws, mus_s_out,
                                                Sigs_ws, Sigs_s_out);
}